// Round 3
// baseline (417.300 us; speedup 1.0000x reference)
//
#include <hip/hip_runtime.h>
#include <cstdint>
#include <cstddef>

// ---------------------------------------------------------------------------
// GenEdge R7 (resubmit — R1 bench never ran):
//   cvt    : f32 -> unit-norm f16 tiled layout (write-coalesced) + gmax=0.
//   edge   : 4-wave workgroups (256 thr) - wave w handles row h=base+w,
//            same (wb,half). Grid 2256 (was 9024 1-wave WGs, occupancy-capped
//            at ~2.5 waves/SIMD). Adjacent waves share 12/13 B-rows -> L1/L2.
//            Sign-free SAD (inputs nonneg => ratio in [0,1] exactly):
//            9 ops/elem. Zero-C MFMA init (no per-di acc zeroing).
//            Factored weighting (R6): S0=sum(w*sad), S1=sum(w*sad*ii);
//            di-invariant weights applied once in epilogue; di=12 at w=0.5 in
//            both halves (gy spurious terms cancel in combine).
//   combine: sum halves, e=|gx|+|gy| (border zeroed), block-max -> atomicMax.
//   norm   : divide by global max.
// ---------------------------------------------------------------------------

typedef _Float16 half8 __attribute__((ext_vector_type(8)));
typedef float    f32x4 __attribute__((ext_vector_type(4)));

#define HW   400
#define NP   (HW*HW)
#define CCH  128
#define W16  416                 // padded width (26 groups of 16)
#define ROWE (W16*CCH)           // 53248 f16 elements per padded row
#define PAD  12
#define IEND 388                 // interior: [12, 388)

// f16 cube layout per row: [pg(26)][ks(4)][q(4)][i(16)][j(8)] elements
// offset = pg*2048 + ks*512 + q*128 + i*8 + j
// => a wave's B-frag load for (group, ks) is base + lane*16 B: one coalesced
//    global_load_dwordx4 per (sg, ks).

// ---------------- Phase 1: convert + normalize (write-coalesced) -----------
__global__ void cvt_kernel(const float* __restrict__ cube,
                           _Float16* __restrict__ c16,
                           unsigned* __restrict__ gmax) {
  __shared__ float part[64];    // [i*4 + ks]
  int pg = blockIdx.x;          // 0..25 (pg 25 is all-pad)
  int r  = blockIdx.y;          // 0..399
  int t  = threadIdx.x;         // 0..255: t = ks*64 + q*16 + i
  if (pg == 0 && r == 0 && t == 0) *gmax = 0u;   // every call (re-poisoned ws)
  int i  = t & 15;
  int q  = (t >> 4) & 3;
  int ks = t >> 6;
  int px = pg*16 + i;
  float v[8];
  if (px < HW) {
    const float* src = cube + ((size_t)(r*HW + px))*CCH + ks*32 + q*8;
    #pragma unroll
    for (int j = 0; j < 8; ++j) v[j] = src[j];
  } else {
    #pragma unroll
    for (int j = 0; j < 8; ++j) v[j] = 0.f;
  }
  float ss = 0.f;
  #pragma unroll
  for (int j = 0; j < 8; ++j) ss += v[j]*v[j];
  ss += __shfl_xor(ss, 16);
  ss += __shfl_xor(ss, 32);
  if (q == 0) part[i*4 + ks] = ss;
  __syncthreads();
  f32x4 pp = *(const f32x4*)&part[i*4];
  float tot = pp.x + pp.y + pp.z + pp.w;
  float sc = (tot > 0.f) ? rsqrtf(tot) : 0.f;
  half8 hv;
  #pragma unroll
  for (int j = 0; j < 8; ++j) hv[j] = (_Float16)(v[j]*sc);
  *(half8*)(c16 + (size_t)r*ROWE + pg*2048 + t*8) = hv;
}

// ---------------- Phase 2: banded MFMA + SAD partials ----------------
__global__ __launch_bounds__(256, 5) void edge_kernel(
    const _Float16* __restrict__ c16,
    float* __restrict__ gxp, float* __restrict__ gyp) {
  // 2256 blocks = 8 XCDs x 282; per XCD contiguous quad-row band.
  // Block: 4 waves, wave w -> row h = PAD + qh*4 + w, shared (wb,half).
  const int id   = blockIdx.x;
  const int g    = (id & 7)*282 + (id >> 3);
  const int qh   = g / 24;
  const int rem  = g - qh*24;
  const int h    = PAD + qh*4 + (threadIdx.x >> 6);   // 12..387
  const int wb   = rem >> 1;             // 0..11
  const int half = rem & 1;              // di range half
  const int l  = threadIdx.x & 63;
  const int c  = l & 15, q = l >> 4;
  const int w0 = PAD + 32*wb;
  const int g0 = 2*wb;                   // first B pixel-group (s0 = 32*wb)

  // A-frags: center pixels of row h.  A[m=lane&15][k=q*8+j]
  half8 A[2][4];
  #pragma unroll
  for (int t = 0; t < 2; ++t) {
    int px = w0 + 16*t + c;              // <= 395 < 400
    const _Float16* p = c16 + (size_t)h*ROWE + (px >> 4)*2048 + q*128 + (px & 15)*8;
    #pragma unroll
    for (int ks = 0; ks < 4; ++ks)
      A[t][ks] = *(const half8*)(p + ks*512);
  }

  const float cq = (float)(c - 4*q);     // dj-12 = 16d - 12 - rr + (c-4q)

  // factored accumulators: S0 = sum w*sad, S1 = sum w*sad*ii
  float S0[2][3][4], S1[2][3][4];
  #pragma unroll
  for (int t = 0; t < 2; ++t)
    #pragma unroll
    for (int d = 0; d < 3; ++d)
      #pragma unroll
      for (int rr = 0; rr < 4; ++rr) { S0[t][d][rr] = 0.f; S1[t][d][rr] = 0.f; }

  const f32x4 z4 = {0.f, 0.f, 0.f, 0.f};
  const _Float16* bBase = c16 + g0*2048 + (size_t)l*8;
  // di=12 belongs to BOTH halves at weight 0.5 (see header comment).
  const int diLo = half ? 12 : 0;
  const int diHi = half ? 25 : 13;

  #pragma unroll 1
  for (int di = diLo; di < diHi; ++di) {
    const int r = h + di - PAD;          // 0..399
    const _Float16* rowB = bBase + (size_t)r*ROWE;

    f32x4 acc[2][3];

    #pragma unroll
    for (int ks = 0; ks < 4; ++ks) {
      half8 B0 = *(const half8*)(rowB + 0*2048 + ks*512);
      half8 B1 = *(const half8*)(rowB + 1*2048 + ks*512);
      half8 B2 = *(const half8*)(rowB + 2*2048 + ks*512);
      half8 B3 = *(const half8*)(rowB + 3*2048 + ks*512);
      if (ks == 0) {
        acc[0][0] = __builtin_amdgcn_mfma_f32_16x16x32_f16(A[0][0], B0, z4, 0,0,0);
        acc[0][1] = __builtin_amdgcn_mfma_f32_16x16x32_f16(A[0][0], B1, z4, 0,0,0);
        acc[0][2] = __builtin_amdgcn_mfma_f32_16x16x32_f16(A[0][0], B2, z4, 0,0,0);
        acc[1][0] = __builtin_amdgcn_mfma_f32_16x16x32_f16(A[1][0], B1, z4, 0,0,0);
        acc[1][1] = __builtin_amdgcn_mfma_f32_16x16x32_f16(A[1][0], B2, z4, 0,0,0);
        acc[1][2] = __builtin_amdgcn_mfma_f32_16x16x32_f16(A[1][0], B3, z4, 0,0,0);
      } else {
        acc[0][0] = __builtin_amdgcn_mfma_f32_16x16x32_f16(A[0][ks], B0, acc[0][0], 0,0,0);
        acc[0][1] = __builtin_amdgcn_mfma_f32_16x16x32_f16(A[0][ks], B1, acc[0][1], 0,0,0);
        acc[0][2] = __builtin_amdgcn_mfma_f32_16x16x32_f16(A[0][ks], B2, acc[0][2], 0,0,0);
        acc[1][0] = __builtin_amdgcn_mfma_f32_16x16x32_f16(A[1][ks], B1, acc[1][0], 0,0,0);
        acc[1][1] = __builtin_amdgcn_mfma_f32_16x16x32_f16(A[1][ks], B2, acc[1][1], 0,0,0);
        acc[1][2] = __builtin_amdgcn_mfma_f32_16x16x32_f16(A[1][ks], B3, acc[1][2], 0,0,0);
      }
    }

    // per-di scalars only; all per-element weighting deferred to epilogue.
    // ratio >= 0 guaranteed (nonneg unit vectors) -> no sign reflection.
    const float ii  = (float)((di <= 12) ? di : 24 - di);
    const float w0s = (di == 12) ? 0.5f : 1.0f;
    const float w1s = w0s * ii;

    #pragma unroll
    for (int t = 0; t < 2; ++t)
      #pragma unroll
      for (int d = 0; d < 3; ++d)
        #pragma unroll
        for (int rr = 0; rr < 4; ++rr) {
          float x  = acc[t][d][rr];                    // cos in [0, 1+eps)
          float sq = __builtin_amdgcn_sqrtf(fmaxf(1.0f - x, 0.0f));
          float pl = fmaf(x, -0.0187292994f, 0.0742610134f);
          pl = fmaf(pl, x, -0.2121143967f);
          pl = fmaf(pl, x,  1.5707287572f);
          float sad = sq * pl;                         // acos(x), |err|<7e-5
          S0[t][d][rr] = fmaf(sad, w0s, S0[t][d][rr]);
          S1[t][d][rr] = fmaf(sad, w1s, S1[t][d][rr]);
        }
  }

  // epilogue: apply di-invariant weights once.
  //   kx = p + sg*ii            -> gx = p*S0 + sg*S1
  //   ky = s_h*(12 + mnj - ii)  -> gy = s_h*((12+mnj)*S0 - S1)
  const float s_h = half ? 1.0f : -1.0f;
  float gx[2][4], gy[2][4];
  #pragma unroll
  for (int t = 0; t < 2; ++t)
    #pragma unroll
    for (int rr = 0; rr < 4; ++rr) { gx[t][rr] = 0.f; gy[t][rr] = 0.f; }

  #pragma unroll
  for (int d = 0; d < 3; ++d)
    #pragma unroll
    for (int rr = 0; rr < 4; ++rr) {
      float p   = cq + (float)(16*d - 12 - rr);   // dj - 12 (integer)
      float ap  = fabsf(p);
      float mnj = 12.0f - ap;                     // >=0 iff |dj-12|<=12
      bool  ok  = mnj >= 0.0f;
      float sg  = fminf(fmaxf(p, -1.0f), 1.0f);   // sgn(p)
      float wy  = 12.0f + mnj;
      #pragma unroll
      for (int t = 0; t < 2; ++t) {
        float s0 = S0[t][d][rr], s1 = S1[t][d][rr];
        float gxc = ok ? fmaf(sg, s1, p*s0) : 0.0f;
        float gyc = ok ? s_h*fmaf(wy, s0, -s1) : 0.0f;
        gx[t][rr] += gxc;
        gy[t][rr] += gyc;
      }
    }

  // reduce over c (lane bits 0..3); writer lanes c == rr store partials
  const int hoff = half*NP + h*HW;
  #pragma unroll
  for (int t = 0; t < 2; ++t)
    #pragma unroll
    for (int rr = 0; rr < 4; ++rr) {
      float sgx = gx[t][rr], sgy = gy[t][rr];
      #pragma unroll
      for (int m = 1; m < 16; m <<= 1) {
        sgx += __shfl_xor(sgx, m);
        sgy += __shfl_xor(sgy, m);
      }
      if (c == rr) {
        int w = w0 + 16*t + 4*q + rr;    // <= 395
        gxp[hoff + w] = sgx;
        gyp[hoff + w] = sgy;
      }
    }
}

// ---------------- Phase 3a: combine halves + global max ----------------
__global__ void combine_kernel(float* __restrict__ gxp,
                               const float* __restrict__ gyp,
                               unsigned* __restrict__ gmax) {
  __shared__ float wm[4];
  int idx = blockIdx.x*256 + threadIdx.x;      // 625*256 = NP exactly
  int hh = idx / HW;
  int ww = idx - hh*HW;
  float e = 0.f;
  if (hh >= PAD && hh < IEND && ww >= PAD && ww < IEND)
    e = fabsf(gxp[idx] + gxp[NP + idx]) + fabsf(gyp[idx] + gyp[NP + idx]);
  gxp[idx] = e;                                // edge buffer aliases gxp[0]
  float m = e;
  #pragma unroll
  for (int off = 1; off < 64; off <<= 1) m = fmaxf(m, __shfl_xor(m, off));
  if ((threadIdx.x & 63) == 0) wm[threadIdx.x >> 6] = m;
  __syncthreads();
  if (threadIdx.x == 0) {
    float mm = fmaxf(fmaxf(wm[0], wm[1]), fmaxf(wm[2], wm[3]));
    atomicMax(gmax, __float_as_uint(mm));      // e >= 0: uint order ok
  }
}

// ---------------- Phase 3b: normalize ----------------
__global__ void norm_kernel(const float* __restrict__ edge,
                            const unsigned* __restrict__ gmax,
                            float* __restrict__ out) {
  int idx = blockIdx.x*256 + threadIdx.x;
  float mv = __uint_as_float(*gmax);
  out[idx] = edge[idx] / mv;                   // border already 0
}

// ---------------- launch ----------------
extern "C" void kernel_launch(void* const* d_in, const int* in_sizes, int n_in,
                              void* d_out, int out_size, void* d_ws, size_t ws_size,
                              hipStream_t stream) {
  const float* cube = (const float*)d_in[0];   // (1,400,400,128) f32
  char* ws = (char*)d_ws;
  _Float16* c16  = (_Float16*)(ws);                     // 42,598,400 B
  float*    gxp  = (float*)(ws + 42598400);             // 2*NP floats
  float*    gyp  = (float*)(ws + 42598400 + 8*NP);      // 2*NP floats
  unsigned* gmax = (unsigned*)(ws + 42598400 + 16*NP);  // 4 B  (~45.2 MB total)

  cvt_kernel<<<dim3(26, 400), 256, 0, stream>>>(cube, c16, gmax);
  edge_kernel<<<2256, 256, 0, stream>>>(c16, gxp, gyp);
  combine_kernel<<<NP/256, 256, 0, stream>>>(gxp, gyp, gmax);
  norm_kernel<<<NP/256, 256, 0, stream>>>(gxp, gmax, (float*)d_out);
}

// Round 4
// 334.356 us; speedup vs baseline: 1.2481x; 1.2481x over previous
//
#include <hip/hip_runtime.h>
#include <cstdint>
#include <cstddef>

// ---------------------------------------------------------------------------
// GenEdge R8:
//   cvt    : f32 -> unit-norm f16 tiled layout (write-coalesced) + gmax=0
//            + zeroes gx/gy accumulation planes (edge uses atomicAdd).
//   edge   : di QUARTER-split (4 blocks x 7 di, shared boundary di at w=0.5;
//            di=12 gy spurious terms cancel between q1/q2). Block = 4 waves,
//            SAME row h, SAME quarter, 4 adjacent wb -> waves share B lines
//            (L1) and resident L2 window stays ~3.6 MB < 4 MB/XCD.
//            48 waves per output row -> 16 waves/CU occupancy without the
//            R7 thrash. __launch_bounds__(256,4): 128-reg cap, no spill
//            (R6's identical loop compiled to ~88 regs).
//            Factored weighting: S0=sum(w*sad), S1=sum(w*sad*ii); epilogue
//            gx = p*S0 + sg*S1, gy = s_h*((12+mnj)*S0 - S1), s_h=+-1/quarter.
//            Partials merged via atomicAdd into single gx/gy planes.
//   combine: e=|gx|+|gy| (border zeroed), block-max -> atomicMax.
//   norm   : divide by global max.
// ---------------------------------------------------------------------------

typedef _Float16 half8 __attribute__((ext_vector_type(8)));
typedef float    f32x4 __attribute__((ext_vector_type(4)));

#define HW   400
#define NP   (HW*HW)
#define CCH  128
#define W16  416                 // padded width (26 groups of 16)
#define ROWE (W16*CCH)           // 53248 f16 elements per padded row
#define PAD  12
#define IEND 388                 // interior: [12, 388)

// f16 cube layout per row: [pg(26)][ks(4)][q(4)][i(16)][j(8)] elements
// offset = pg*2048 + ks*512 + q*128 + i*8 + j
// => a wave's B-frag load for (group, ks) is base + lane*16 B: one coalesced
//    global_load_dwordx4 per (group, ks).

// ---------------- Phase 1: convert + normalize (write-coalesced) -----------
__global__ void cvt_kernel(const float* __restrict__ cube,
                           _Float16* __restrict__ c16,
                           float* __restrict__ gxp, float* __restrict__ gyp,
                           unsigned* __restrict__ gmax) {
  __shared__ float part[64];    // [i*4 + ks]
  int pg = blockIdx.x;          // 0..25 (pg 25 is all-pad)
  int r  = blockIdx.y;          // 0..399
  int t  = threadIdx.x;         // 0..255: t = ks*64 + q*16 + i
  if (pg == 0 && r == 0 && t == 0) *gmax = 0u;   // every call (re-poisoned ws)
  // zero the atomic accumulation planes (covers [0,NP) since 26*400*256 >> NP)
  int flat = (r*26 + pg)*256 + t;
  if (flat < NP) { gxp[flat] = 0.f; gyp[flat] = 0.f; }
  int i  = t & 15;
  int q  = (t >> 4) & 3;
  int ks = t >> 6;
  int px = pg*16 + i;
  float v[8];
  if (px < HW) {
    const float* src = cube + ((size_t)(r*HW + px))*CCH + ks*32 + q*8;
    #pragma unroll
    for (int j = 0; j < 8; ++j) v[j] = src[j];
  } else {
    #pragma unroll
    for (int j = 0; j < 8; ++j) v[j] = 0.f;
  }
  float ss = 0.f;
  #pragma unroll
  for (int j = 0; j < 8; ++j) ss += v[j]*v[j];
  ss += __shfl_xor(ss, 16);
  ss += __shfl_xor(ss, 32);
  if (q == 0) part[i*4 + ks] = ss;
  __syncthreads();
  f32x4 pp = *(const f32x4*)&part[i*4];
  float tot = pp.x + pp.y + pp.z + pp.w;
  float sc = (tot > 0.f) ? rsqrtf(tot) : 0.f;
  half8 hv;
  #pragma unroll
  for (int j = 0; j < 8; ++j) hv[j] = (_Float16)(v[j]*sc);
  *(half8*)(c16 + (size_t)r*ROWE + pg*2048 + t*8) = hv;
}

// ---------------- Phase 2: banded MFMA + SAD partials ----------------
__global__ __launch_bounds__(256, 4) void edge_kernel(
    const _Float16* __restrict__ c16,
    float* __restrict__ gxp, float* __restrict__ gyp) {
  // 4512 blocks = 8 XCDs x 564. Per row: 12 blocks (3 wb-quads x 4 quarters).
  // Block: 4 waves, wave wv -> wb = wbq*4 + wv, all SAME row h and quarter.
  const int id  = blockIdx.x;
  const int g   = (id & 7)*564 + (id >> 3);
  const int row = g / 12;                // 0..375
  const int rem = g - row*12;            // wbq*4 + qrt
  const int qrt = rem & 3;               // di quarter 0..3
  const int wbq = rem >> 2;              // 0..2
  const int h   = row + PAD;             // 12..387
  const int wv  = threadIdx.x >> 6;      // wave 0..3
  const int wb  = wbq*4 + wv;            // 0..11
  const int l   = threadIdx.x & 63;
  const int c   = l & 15, q = l >> 4;
  const int w0  = PAD + 32*wb;
  const int g0  = 2*wb;                  // first B pixel-group

  // A-frags: center pixels of row h.  A[m=lane&15][k=q*8+j]
  half8 A[2][4];
  #pragma unroll
  for (int t = 0; t < 2; ++t) {
    int px = w0 + 16*t + c;              // <= 395 < 400
    const _Float16* p = c16 + (size_t)h*ROWE + (px >> 4)*2048 + q*128 + (px & 15)*8;
    #pragma unroll
    for (int ks = 0; ks < 4; ++ks)
      A[t][ks] = *(const half8*)(p + ks*512);
  }

  const float cq = (float)(c - 4*q);     // dj-12 = 16d - 12 - rr + (c-4q)

  // factored accumulators: S0 = sum w*sad, S1 = sum w*sad*ii
  float S0[2][3][4], S1[2][3][4];
  #pragma unroll
  for (int t = 0; t < 2; ++t)
    #pragma unroll
    for (int d = 0; d < 3; ++d)
      #pragma unroll
      for (int rr = 0; rr < 4; ++rr) { S0[t][d][rr] = 0.f; S1[t][d][rr] = 0.f; }

  const f32x4 z4 = {0.f, 0.f, 0.f, 0.f};
  const _Float16* bBase = c16 + g0*2048 + (size_t)l*8;
  // quarter di range [6q, 6q+6]; shared boundary values get w = 0.5.
  const int diLo = 6*qrt;
  const int diHi = 6*qrt + 7;

  #pragma unroll 1
  for (int di = diLo; di < diHi; ++di) {
    const int r = h + di - PAD;          // 0..399
    const _Float16* rowB = bBase + (size_t)r*ROWE;

    f32x4 acc[2][3];

    #pragma unroll
    for (int ks = 0; ks < 4; ++ks) {
      half8 B0 = *(const half8*)(rowB + 0*2048 + ks*512);
      half8 B1 = *(const half8*)(rowB + 1*2048 + ks*512);
      half8 B2 = *(const half8*)(rowB + 2*2048 + ks*512);
      half8 B3 = *(const half8*)(rowB + 3*2048 + ks*512);
      if (ks == 0) {
        acc[0][0] = __builtin_amdgcn_mfma_f32_16x16x32_f16(A[0][0], B0, z4, 0,0,0);
        acc[0][1] = __builtin_amdgcn_mfma_f32_16x16x32_f16(A[0][0], B1, z4, 0,0,0);
        acc[0][2] = __builtin_amdgcn_mfma_f32_16x16x32_f16(A[0][0], B2, z4, 0,0,0);
        acc[1][0] = __builtin_amdgcn_mfma_f32_16x16x32_f16(A[1][0], B1, z4, 0,0,0);
        acc[1][1] = __builtin_amdgcn_mfma_f32_16x16x32_f16(A[1][0], B2, z4, 0,0,0);
        acc[1][2] = __builtin_amdgcn_mfma_f32_16x16x32_f16(A[1][0], B3, z4, 0,0,0);
      } else {
        acc[0][0] = __builtin_amdgcn_mfma_f32_16x16x32_f16(A[0][ks], B0, acc[0][0], 0,0,0);
        acc[0][1] = __builtin_amdgcn_mfma_f32_16x16x32_f16(A[0][ks], B1, acc[0][1], 0,0,0);
        acc[0][2] = __builtin_amdgcn_mfma_f32_16x16x32_f16(A[0][ks], B2, acc[0][2], 0,0,0);
        acc[1][0] = __builtin_amdgcn_mfma_f32_16x16x32_f16(A[1][ks], B1, acc[1][0], 0,0,0);
        acc[1][1] = __builtin_amdgcn_mfma_f32_16x16x32_f16(A[1][ks], B2, acc[1][1], 0,0,0);
        acc[1][2] = __builtin_amdgcn_mfma_f32_16x16x32_f16(A[1][ks], B3, acc[1][2], 0,0,0);
      }
    }

    // per-di scalars only; all per-element weighting deferred to epilogue.
    // ratio >= 0 guaranteed (nonneg unit vectors) -> no sign reflection.
    const float ii  = (float)((di <= 12) ? di : 24 - di);
    const bool  shared = (di == diLo && qrt != 0) || (di == diHi-1 && qrt != 3);
    const float w0s = shared ? 0.5f : 1.0f;
    const float w1s = w0s * ii;

    #pragma unroll
    for (int t = 0; t < 2; ++t)
      #pragma unroll
      for (int d = 0; d < 3; ++d)
        #pragma unroll
        for (int rr = 0; rr < 4; ++rr) {
          float x  = acc[t][d][rr];                    // cos in [0, 1+eps)
          float sq = __builtin_amdgcn_sqrtf(fmaxf(1.0f - x, 0.0f));
          float pl = fmaf(x, -0.0187292994f, 0.0742610134f);
          pl = fmaf(pl, x, -0.2121143967f);
          pl = fmaf(pl, x,  1.5707287572f);
          float sad = sq * pl;                         // acos(x), |err|<7e-5
          S0[t][d][rr] = fmaf(sad, w0s, S0[t][d][rr]);
          S1[t][d][rr] = fmaf(sad, w1s, S1[t][d][rr]);
        }
  }

  // epilogue: apply di-invariant weights once.
  //   kx = p + sg*ii            -> gx = p*S0 + sg*S1
  //   ky = s_h*(12 + mnj - ii)  -> gy = s_h*((12+mnj)*S0 - S1)
  // (dif = di-12 = s_h*(12-ii) within a quarter; s_h = sign of di-12.)
  const float s_h = (qrt >= 2) ? 1.0f : -1.0f;
  float gx[2][4], gy[2][4];
  #pragma unroll
  for (int t = 0; t < 2; ++t)
    #pragma unroll
    for (int rr = 0; rr < 4; ++rr) { gx[t][rr] = 0.f; gy[t][rr] = 0.f; }

  #pragma unroll
  for (int d = 0; d < 3; ++d)
    #pragma unroll
    for (int rr = 0; rr < 4; ++rr) {
      float p   = cq + (float)(16*d - 12 - rr);   // dj - 12 (integer)
      float ap  = fabsf(p);
      float mnj = 12.0f - ap;                     // >=0 iff |dj-12|<=12
      bool  ok  = mnj >= 0.0f;
      float sg  = fminf(fmaxf(p, -1.0f), 1.0f);   // sgn(p)
      float wy  = 12.0f + mnj;
      #pragma unroll
      for (int t = 0; t < 2; ++t) {
        float s0 = S0[t][d][rr], s1 = S1[t][d][rr];
        float gxc = ok ? fmaf(sg, s1, p*s0) : 0.0f;
        float gyc = ok ? s_h*fmaf(wy, s0, -s1) : 0.0f;
        gx[t][rr] += gxc;
        gy[t][rr] += gyc;
      }
    }

  // reduce over c (lane bits 0..3); writer lanes c == rr add partials
  const int hoff = h*HW;
  #pragma unroll
  for (int t = 0; t < 2; ++t)
    #pragma unroll
    for (int rr = 0; rr < 4; ++rr) {
      float sgx = gx[t][rr], sgy = gy[t][rr];
      #pragma unroll
      for (int m = 1; m < 16; m <<= 1) {
        sgx += __shfl_xor(sgx, m);
        sgy += __shfl_xor(sgy, m);
      }
      if (c == rr) {
        int w = w0 + 16*t + 4*q + rr;    // <= 395
        atomicAdd(&gxp[hoff + w], sgx);
        atomicAdd(&gyp[hoff + w], sgy);
      }
    }
}

// ---------------- Phase 3a: combine + global max ----------------
__global__ void combine_kernel(float* __restrict__ gxp,
                               const float* __restrict__ gyp,
                               unsigned* __restrict__ gmax) {
  __shared__ float wm[4];
  int idx = blockIdx.x*256 + threadIdx.x;      // 625*256 = NP exactly
  int hh = idx / HW;
  int ww = idx - hh*HW;
  float e = 0.f;
  if (hh >= PAD && hh < IEND && ww >= PAD && ww < IEND)
    e = fabsf(gxp[idx]) + fabsf(gyp[idx]);
  gxp[idx] = e;                                // edge buffer aliases gxp
  float m = e;
  #pragma unroll
  for (int off = 1; off < 64; off <<= 1) m = fmaxf(m, __shfl_xor(m, off));
  if ((threadIdx.x & 63) == 0) wm[threadIdx.x >> 6] = m;
  __syncthreads();
  if (threadIdx.x == 0) {
    float mm = fmaxf(fmaxf(wm[0], wm[1]), fmaxf(wm[2], wm[3]));
    atomicMax(gmax, __float_as_uint(mm));      // e >= 0: uint order ok
  }
}

// ---------------- Phase 3b: normalize ----------------
__global__ void norm_kernel(const float* __restrict__ edge,
                            const unsigned* __restrict__ gmax,
                            float* __restrict__ out) {
  int idx = blockIdx.x*256 + threadIdx.x;
  float mv = __uint_as_float(*gmax);
  out[idx] = edge[idx] / mv;                   // border already 0
}

// ---------------- launch ----------------
extern "C" void kernel_launch(void* const* d_in, const int* in_sizes, int n_in,
                              void* d_out, int out_size, void* d_ws, size_t ws_size,
                              hipStream_t stream) {
  const float* cube = (const float*)d_in[0];   // (1,400,400,128) f32
  char* ws = (char*)d_ws;
  _Float16* c16  = (_Float16*)(ws);                     // 42,598,400 B
  float*    gxp  = (float*)(ws + 42598400);             // NP floats
  float*    gyp  = (float*)(ws + 42598400 + 4*NP);      // NP floats
  unsigned* gmax = (unsigned*)(ws + 42598400 + 8*NP);   // 4 B (~43.9 MB total)

  cvt_kernel<<<dim3(26, 400), 256, 0, stream>>>(cube, c16, gxp, gyp, gmax);
  edge_kernel<<<4512, 256, 0, stream>>>(c16, gxp, gyp);
  combine_kernel<<<NP/256, 256, 0, stream>>>(gxp, gyp, gmax);
  norm_kernel<<<NP/256, 256, 0, stream>>>(gxp, gmax, (float*)d_out);
}

// Round 6
// 216.847 us; speedup vs baseline: 1.9244x; 1.5419x over previous
//
#include <hip/hip_runtime.h>
#include <cstdint>
#include <cstddef>

// ---------------------------------------------------------------------------
// GenEdge R9 (resubmit — R4 bench never ran):
//   cvt    : f32 -> unit-norm f16 tiled layout (write-coalesced) + gmax=0.
//   edge   : half-split di (13 iters each, di=12 shared at w=0.5; gy spurious
//            terms cancel in combine). Block = 4 waves, SAME row h, SAME half,
//            adjacent wb (wb = wbq*4+wv) -> disjoint output columns => plain
//            stores (NO atomics - R8's 64B-line RMW at the coherence point was
//            the regression), and adjacent-wb waves share half their B lines
//            (L1). Grid 2256 = 376 rows x 2 halves x 3 wbq; 4-wave WGs beat
//            the 1-wave CP launch-rate cap (R6: 32% occ). launch_bounds(256,3)
//            -> 170-reg cap: no spill (demand ~135; R7's 96 / R8's 128 caps
//            both spilled). Factored weighting + sign-free SAD + zero-C init.
//   combine: sum halves, e=|gx|+|gy| (border zeroed), block-max -> atomicMax.
//   norm   : divide by global max.
// ---------------------------------------------------------------------------

typedef _Float16 half8 __attribute__((ext_vector_type(8)));
typedef float    f32x4 __attribute__((ext_vector_type(4)));

#define HW   400
#define NP   (HW*HW)
#define CCH  128
#define W16  416                 // padded width (26 groups of 16)
#define ROWE (W16*CCH)           // 53248 f16 elements per padded row
#define PAD  12
#define IEND 388                 // interior: [12, 388)

// f16 cube layout per row: [pg(26)][ks(4)][q(4)][i(16)][j(8)] elements
// offset = pg*2048 + ks*512 + q*128 + i*8 + j
// => a wave's B-frag load for (group, ks) is base + lane*16 B: one coalesced
//    global_load_dwordx4 per (group, ks).

// ---------------- Phase 1: convert + normalize (write-coalesced) -----------
__global__ void cvt_kernel(const float* __restrict__ cube,
                           _Float16* __restrict__ c16,
                           unsigned* __restrict__ gmax) {
  __shared__ float part[64];    // [i*4 + ks]
  int pg = blockIdx.x;          // 0..25 (pg 25 is all-pad)
  int r  = blockIdx.y;          // 0..399
  int t  = threadIdx.x;         // 0..255: t = ks*64 + q*16 + i
  if (pg == 0 && r == 0 && t == 0) *gmax = 0u;   // every call (re-poisoned ws)
  int i  = t & 15;
  int q  = (t >> 4) & 3;
  int ks = t >> 6;
  int px = pg*16 + i;
  float v[8];
  if (px < HW) {
    const float* src = cube + ((size_t)(r*HW + px))*CCH + ks*32 + q*8;
    #pragma unroll
    for (int j = 0; j < 8; ++j) v[j] = src[j];
  } else {
    #pragma unroll
    for (int j = 0; j < 8; ++j) v[j] = 0.f;
  }
  float ss = 0.f;
  #pragma unroll
  for (int j = 0; j < 8; ++j) ss += v[j]*v[j];
  ss += __shfl_xor(ss, 16);
  ss += __shfl_xor(ss, 32);
  if (q == 0) part[i*4 + ks] = ss;
  __syncthreads();
  f32x4 pp = *(const f32x4*)&part[i*4];
  float tot = pp.x + pp.y + pp.z + pp.w;
  float sc = (tot > 0.f) ? rsqrtf(tot) : 0.f;
  half8 hv;
  #pragma unroll
  for (int j = 0; j < 8; ++j) hv[j] = (_Float16)(v[j]*sc);
  *(half8*)(c16 + (size_t)r*ROWE + pg*2048 + t*8) = hv;
}

// ---------------- Phase 2: banded MFMA + SAD partials ----------------
__global__ __launch_bounds__(256, 3) void edge_kernel(
    const _Float16* __restrict__ c16,
    float* __restrict__ gxp, float* __restrict__ gyp) {
  // 2256 blocks = 8 XCDs x 282; per XCD contiguous row band.
  // Block: 4 waves, wave wv -> wb = wbq*4 + wv, all SAME row h and half.
  const int id  = blockIdx.x;
  const int g   = (id & 7)*282 + (id >> 3);
  const int row = g / 6;                 // 0..375
  const int rem = g - row*6;             // wbq*2 + half
  const int half = rem & 1;              // di half
  const int wbq  = rem >> 1;             // 0..2
  const int h   = row + PAD;             // 12..387
  const int wv  = threadIdx.x >> 6;      // wave 0..3
  const int wb  = wbq*4 + wv;            // 0..11
  const int l   = threadIdx.x & 63;
  const int c   = l & 15, q = l >> 4;
  const int w0  = PAD + 32*wb;
  const int g0  = 2*wb;                  // first B pixel-group

  // A-frags: center pixels of row h.  A[m=lane&15][k=q*8+j]
  half8 A[2][4];
  #pragma unroll
  for (int t = 0; t < 2; ++t) {
    int px = w0 + 16*t + c;              // <= 395 < 400
    const _Float16* p = c16 + (size_t)h*ROWE + (px >> 4)*2048 + q*128 + (px & 15)*8;
    #pragma unroll
    for (int ks = 0; ks < 4; ++ks)
      A[t][ks] = *(const half8*)(p + ks*512);
  }

  const float cq = (float)(c - 4*q);     // dj-12 = 16d - 12 - rr + (c-4q)

  // factored accumulators: S0 = sum w*sad, S1 = sum w*sad*ii
  float S0[2][3][4], S1[2][3][4];
  #pragma unroll
  for (int t = 0; t < 2; ++t)
    #pragma unroll
    for (int d = 0; d < 3; ++d)
      #pragma unroll
      for (int rr = 0; rr < 4; ++rr) { S0[t][d][rr] = 0.f; S1[t][d][rr] = 0.f; }

  const f32x4 z4 = {0.f, 0.f, 0.f, 0.f};
  const _Float16* bBase = c16 + g0*2048 + (size_t)l*8;
  // di=12 belongs to BOTH halves at weight 0.5.
  const int diLo = half ? 12 : 0;
  const int diHi = half ? 25 : 13;

  #pragma unroll 1
  for (int di = diLo; di < diHi; ++di) {
    const int r = h + di - PAD;          // 0..399
    const _Float16* rowB = bBase + (size_t)r*ROWE;

    f32x4 acc[2][3];

    #pragma unroll
    for (int ks = 0; ks < 4; ++ks) {
      half8 B0 = *(const half8*)(rowB + 0*2048 + ks*512);
      half8 B1 = *(const half8*)(rowB + 1*2048 + ks*512);
      half8 B2 = *(const half8*)(rowB + 2*2048 + ks*512);
      half8 B3 = *(const half8*)(rowB + 3*2048 + ks*512);
      if (ks == 0) {
        acc[0][0] = __builtin_amdgcn_mfma_f32_16x16x32_f16(A[0][0], B0, z4, 0,0,0);
        acc[0][1] = __builtin_amdgcn_mfma_f32_16x16x32_f16(A[0][0], B1, z4, 0,0,0);
        acc[0][2] = __builtin_amdgcn_mfma_f32_16x16x32_f16(A[0][0], B2, z4, 0,0,0);
        acc[1][0] = __builtin_amdgcn_mfma_f32_16x16x32_f16(A[1][0], B1, z4, 0,0,0);
        acc[1][1] = __builtin_amdgcn_mfma_f32_16x16x32_f16(A[1][0], B2, z4, 0,0,0);
        acc[1][2] = __builtin_amdgcn_mfma_f32_16x16x32_f16(A[1][0], B3, z4, 0,0,0);
      } else {
        acc[0][0] = __builtin_amdgcn_mfma_f32_16x16x32_f16(A[0][ks], B0, acc[0][0], 0,0,0);
        acc[0][1] = __builtin_amdgcn_mfma_f32_16x16x32_f16(A[0][ks], B1, acc[0][1], 0,0,0);
        acc[0][2] = __builtin_amdgcn_mfma_f32_16x16x32_f16(A[0][ks], B2, acc[0][2], 0,0,0);
        acc[1][0] = __builtin_amdgcn_mfma_f32_16x16x32_f16(A[1][ks], B1, acc[1][0], 0,0,0);
        acc[1][1] = __builtin_amdgcn_mfma_f32_16x16x32_f16(A[1][ks], B2, acc[1][1], 0,0,0);
        acc[1][2] = __builtin_amdgcn_mfma_f32_16x16x32_f16(A[1][ks], B3, acc[1][2], 0,0,0);
      }
    }

    // per-di scalars only; all per-element weighting deferred to epilogue.
    // ratio >= 0 guaranteed (nonneg unit vectors) -> no sign reflection.
    const float ii  = (float)((di <= 12) ? di : 24 - di);
    const float w0s = (di == 12) ? 0.5f : 1.0f;
    const float w1s = w0s * ii;

    #pragma unroll
    for (int t = 0; t < 2; ++t)
      #pragma unroll
      for (int d = 0; d < 3; ++d)
        #pragma unroll
        for (int rr = 0; rr < 4; ++rr) {
          float x  = acc[t][d][rr];                    // cos in [0, 1+eps)
          float sq = __builtin_amdgcn_sqrtf(fmaxf(1.0f - x, 0.0f));
          float pl = fmaf(x, -0.0187292994f, 0.0742610134f);
          pl = fmaf(pl, x, -0.2121143967f);
          pl = fmaf(pl, x,  1.5707287572f);
          float sad = sq * pl;                         // acos(x), |err|<7e-5
          S0[t][d][rr] = fmaf(sad, w0s, S0[t][d][rr]);
          S1[t][d][rr] = fmaf(sad, w1s, S1[t][d][rr]);
        }
  }

  // epilogue: apply di-invariant weights once.
  //   kx = p + sg*ii            -> gx = p*S0 + sg*S1
  //   ky = s_h*(12 + mnj - ii)  -> gy = s_h*((12+mnj)*S0 - S1)
  const float s_h = half ? 1.0f : -1.0f;
  float gx[2][4], gy[2][4];
  #pragma unroll
  for (int t = 0; t < 2; ++t)
    #pragma unroll
    for (int rr = 0; rr < 4; ++rr) { gx[t][rr] = 0.f; gy[t][rr] = 0.f; }

  #pragma unroll
  for (int d = 0; d < 3; ++d)
    #pragma unroll
    for (int rr = 0; rr < 4; ++rr) {
      float p   = cq + (float)(16*d - 12 - rr);   // dj - 12 (integer)
      float ap  = fabsf(p);
      float mnj = 12.0f - ap;                     // >=0 iff |dj-12|<=12
      bool  ok  = mnj >= 0.0f;
      float sg  = fminf(fmaxf(p, -1.0f), 1.0f);   // sgn(p)
      float wy  = 12.0f + mnj;
      #pragma unroll
      for (int t = 0; t < 2; ++t) {
        float s0 = S0[t][d][rr], s1 = S1[t][d][rr];
        float gxc = ok ? fmaf(sg, s1, p*s0) : 0.0f;
        float gyc = ok ? s_h*fmaf(wy, s0, -s1) : 0.0f;
        gx[t][rr] += gxc;
        gy[t][rr] += gyc;
      }
    }

  // reduce over c (lane bits 0..3); writer lanes c == rr store partials
  const int hoff = half*NP + h*HW;
  #pragma unroll
  for (int t = 0; t < 2; ++t)
    #pragma unroll
    for (int rr = 0; rr < 4; ++rr) {
      float sgx = gx[t][rr], sgy = gy[t][rr];
      #pragma unroll
      for (int m = 1; m < 16; m <<= 1) {
        sgx += __shfl_xor(sgx, m);
        sgy += __shfl_xor(sgy, m);
      }
      if (c == rr) {
        int w = w0 + 16*t + 4*q + rr;    // <= 395, disjoint across waves
        gxp[hoff + w] = sgx;
        gyp[hoff + w] = sgy;
      }
    }
}

// ---------------- Phase 3a: combine halves + global max ----------------
__global__ void combine_kernel(float* __restrict__ gxp,
                               const float* __restrict__ gyp,
                               unsigned* __restrict__ gmax) {
  __shared__ float wm[4];
  int idx = blockIdx.x*256 + threadIdx.x;      // 625*256 = NP exactly
  int hh = idx / HW;
  int ww = idx - hh*HW;
  float e = 0.f;
  if (hh >= PAD && hh < IEND && ww >= PAD && ww < IEND)
    e = fabsf(gxp[idx] + gxp[NP + idx]) + fabsf(gyp[idx] + gyp[NP + idx]);
  gxp[idx] = e;                                // edge buffer aliases gxp[0]
  float m = e;
  #pragma unroll
  for (int off = 1; off < 64; off <<= 1) m = fmaxf(m, __shfl_xor(m, off));
  if ((threadIdx.x & 63) == 0) wm[threadIdx.x >> 6] = m;
  __syncthreads();
  if (threadIdx.x == 0) {
    float mm = fmaxf(fmaxf(wm[0], wm[1]), fmaxf(wm[2], wm[3]));
    atomicMax(gmax, __float_as_uint(mm));      // e >= 0: uint order ok
  }
}

// ---------------- Phase 3b: normalize ----------------
__global__ void norm_kernel(const float* __restrict__ edge,
                            const unsigned* __restrict__ gmax,
                            float* __restrict__ out) {
  int idx = blockIdx.x*256 + threadIdx.x;
  float mv = __uint_as_float(*gmax);
  out[idx] = edge[idx] / mv;                   // border already 0
}

// ---------------- launch ----------------
extern "C" void kernel_launch(void* const* d_in, const int* in_sizes, int n_in,
                              void* d_out, int out_size, void* d_ws, size_t ws_size,
                              hipStream_t stream) {
  const float* cube = (const float*)d_in[0];   // (1,400,400,128) f32
  char* ws = (char*)d_ws;
  _Float16* c16  = (_Float16*)(ws);                     // 42,598,400 B
  float*    gxp  = (float*)(ws + 42598400);             // 2*NP floats
  float*    gyp  = (float*)(ws + 42598400 + 8*NP);      // 2*NP floats
  unsigned* gmax = (unsigned*)(ws + 42598400 + 16*NP);  // 4 B  (~45.2 MB total)

  cvt_kernel<<<dim3(26, 400), 256, 0, stream>>>(cube, c16, gmax);
  edge_kernel<<<2256, 256, 0, stream>>>(c16, gxp, gyp);
  combine_kernel<<<NP/256, 256, 0, stream>>>(gxp, gyp, gmax);
  norm_kernel<<<NP/256, 256, 0, stream>>>(gxp, gmax, (float*)d_out);
}